// Round 8
// baseline (115.967 us; speedup 1.0000x reference)
//
#include <hip/hip_runtime.h>

#define NN 8192
#define DIN 7
#define DH 8
#define DOUT 23
#define CUTOFF 3.6f
#define SLOPE 0.01f

#define JC 256               // j-chunk per k3 block
#define ROWS 256             // rows per k3 block (4 waves x 4 tiles x 16)
#define PPITCH 264           // padded row pitch (shorts): 528B, bank offset rotates by 4/q
#define NJS (JC / 32)        // 8 K-steps of 32

typedef float  v4f __attribute__((ext_vector_type(4)));
typedef short  v8s __attribute__((ext_vector_type(8)));
typedef unsigned int v4u __attribute__((ext_vector_type(4)));

__device__ __forceinline__ float leaky(float v) { return v >= 0.0f ? v : SLOPE * v; }

// Per-node feature pipeline. Single shared implementation so k3's staged E/ev and
// k4's recomputed E/ev are bit-identical up to the bf16 split (diagonal cancel).
__device__ __forceinline__ void node_feats(
    const float* __restrict__ x,
    const float* __restrict__ W1, const float* __restrict__ b1,
    const float* __restrict__ W2, const float* __restrict__ b2,
    const float* __restrict__ W3, const float* __restrict__ b3,
    int n, float coord[3], float& E, float ev[7])
{
    float xi[DIN];
#pragma unroll
    for (int d = 0; d < DIN; ++d) xi[d] = x[n * DIN + d];
    coord[0] = xi[0]; coord[1] = xi[1]; coord[2] = xi[2];

    float h1[DH];
#pragma unroll
    for (int k = 0; k < DH; ++k) {
        float t = b1[k];
#pragma unroll
        for (int d = 0; d < DIN; ++d) t = fmaf(W1[k * DIN + d], xi[d], t);
        h1[k] = leaky(t);
    }
    float h2[DH];
#pragma unroll
    for (int k = 0; k < DH; ++k) {
        float t = b2[k];
#pragma unroll
        for (int d = 0; d < DH; ++d) t = fmaf(W2[k * DH + d], h1[d], t);
        h2[k] = leaky(t);
    }
    float h3[DOUT];
#pragma unroll
    for (int m = 0; m < DOUT; ++m) {
        float t = b3[m];
#pragma unroll
        for (int d = 0; d < DH; ++d) t = fmaf(W3[m * DH + d], h2[d], t);
        h3[m] = t;
    }
    float s = 0.0f;
#pragma unroll
    for (int k = 0; k < 8; ++k) s = fmaf(h3[7 + k], h3[15 + k], s);
    // |s| ~ O(1) (weights scaled 0.1) -> exp without max-shift is safe in fp32;
    // softmax ratio is shift-invariant so this matches the reference.
    E = expf(s);
#pragma unroll
    for (int q = 0; q < 7; ++q) ev[q] = h3[q] * E;
}

// ---------------- K3: C(8192x8) = W(0/1 mask) x P via bf16 MFMA ------------------------
// grid (32, 32): blockIdx.x -> 256-row tile, blockIdx.y -> 256-j chunk.
// 1024 blocks = 4 blocks/CU = 4 waves/SIMD (R7 ran 2/SIMD; testing latency-hiding).
// P split hi+lo bf16 (rel err ~2^-16), masks exact in bf16; both MFMAs chain into fp32 C.
__global__ __launch_bounds__(256, 4) void k3_mfma(
    const float* __restrict__ x,
    const float* __restrict__ W1, const float* __restrict__ b1,
    const float* __restrict__ W2, const float* __restrict__ b2,
    const float* __restrict__ W3, const float* __restrict__ b3,
    float* __restrict__ accum)
{
    __shared__ __attribute__((aligned(16))) float sCx[JC];
    __shared__ __attribute__((aligned(16))) float sCy[JC];
    __shared__ __attribute__((aligned(16))) float sCz[JC];
    __shared__ __attribute__((aligned(16))) short sPhi[8 * PPITCH];
    __shared__ __attribute__((aligned(16))) short sPlo[8 * PPITCH];

    int tid = threadIdx.x;
    int jBase = blockIdx.y * JC;
    int rowBase = blockIdx.x * ROWS;

    // stage: 1 j per thread -> coords f32, P as bf16 hi/lo in [q][j] layout
    {
        int lj = tid;
        int j = jBase + lj;
        float cj[3], E, ev[7];
        node_feats(x, W1, b1, W2, b2, W3, b3, j, cj, E, ev);
        sCx[lj] = cj[0]; sCy[lj] = cj[1]; sCz[lj] = cj[2];
        float pv[8] = {ev[0], ev[1], ev[2], ev[3], ev[4], ev[5], ev[6], E};
#pragma unroll
        for (int q = 0; q < 8; ++q) {
            float v = pv[q];
            unsigned u = __float_as_uint(v);
            float resid = v - __uint_as_float(u & 0xFFFF0000u);   // exact
            sPhi[q * PPITCH + lj] = (short)(u >> 16);
            sPlo[q * PPITCH + lj] = (short)(__float_as_uint(resid) >> 16);
        }
    }

    int wave = tid >> 6;
    int lane = tid & 63;
    int lm = lane & 15;      // A-row within tile / C-col (q)
    int q4 = lane >> 4;      // k-slice quad
    int bcol = lm & 7;       // B-row in [q][j] store; cols 8-15 mirror 0-7 (never stored)

    // row coords for this lane's 4 tiles (row = lane&15 within each 16-row tile)
    float rxt[4], ryt[4], rzt[4];
#pragma unroll
    for (int t = 0; t < 4; ++t) {
        int r = rowBase + wave * 64 + t * 16 + lm;
        rxt[t] = x[r * DIN + 0];
        ryt[t] = x[r * DIN + 1];
        rzt[t] = x[r * DIN + 2];
    }

    v4f c0 = {0.f, 0.f, 0.f, 0.f};
    v4f c1 = {0.f, 0.f, 0.f, 0.f};
    v4f c2 = {0.f, 0.f, 0.f, 0.f};
    v4f c3 = {0.f, 0.f, 0.f, 0.f};

    __syncthreads();

#pragma unroll
    for (int js = 0; js < NJS; ++js) {
        int jb = js * 32 + q4 * 8;      // this lane's 8 consecutive j within the slice
        v8s bhi = *(const v8s*)&sPhi[bcol * PPITCH + jb];
        v8s blo = *(const v8s*)&sPlo[bcol * PPITCH + jb];
        float4 x0 = *(const float4*)&sCx[jb];
        float4 x1 = *(const float4*)&sCx[jb + 4];
        float4 y0 = *(const float4*)&sCy[jb];
        float4 y1 = *(const float4*)&sCy[jb + 4];
        float4 z0 = *(const float4*)&sCz[jb];
        float4 z1 = *(const float4*)&sCz[jb + 4];
        float jx[8] = {x0.x, x0.y, x0.z, x0.w, x1.x, x1.y, x1.z, x1.w};
        float jy[8] = {y0.x, y0.y, y0.z, y0.w, y1.x, y1.y, y1.z, y1.w};
        float jz[8] = {z0.x, z0.y, z0.z, z0.w, z1.x, z1.y, z1.z, z1.w};

#pragma unroll
        for (int t = 0; t < 4; ++t) {
            v4u pk;
#pragma unroll
            for (int i2 = 0; i2 < 4; ++i2) {
                // exact ref order: (|dx| + |dy|) + |dz|
                float ta = fabsf(rxt[t] - jx[2 * i2]) + fabsf(ryt[t] - jy[2 * i2])
                         + fabsf(rzt[t] - jz[2 * i2]);
                float tb = fabsf(rxt[t] - jx[2 * i2 + 1]) + fabsf(ryt[t] - jy[2 * i2 + 1])
                         + fabsf(rzt[t] - jz[2 * i2 + 1]);
                unsigned wa = (ta <= CUTOFF) ? 0x3F80u : 0u;   // bf16 1.0
                unsigned wb = (tb <= CUTOFF) ? 0x3F80u : 0u;
                pk[i2] = wa | (wb << 16);
            }
            v8s a = __builtin_bit_cast(v8s, pk);
            v4f* cp = (t == 0) ? &c0 : (t == 1) ? &c1 : (t == 2) ? &c2 : &c3;
            *cp = __builtin_amdgcn_mfma_f32_16x16x32_bf16(a, bhi, *cp, 0, 0, 0);
            *cp = __builtin_amdgcn_mfma_f32_16x16x32_bf16(a, blo, *cp, 0, 0, 0);
        }
    }

    // C layout: col=lane&15 (q), row=(lane>>4)*4+reg. Only cols 0..7 are real.
    if (lm < 8) {
        v4f cc[4] = {c0, c1, c2, c3};
#pragma unroll
        for (int t = 0; t < 4; ++t) {
            int rb = rowBase + wave * 64 + t * 16 + q4 * 4;
#pragma unroll
            for (int reg = 0; reg < 4; ++reg)
                atomicAdd(&accum[lm * NN + rb + reg], cc[t][reg]);
        }
    }
}

// ---------------- K4: recompute row features, finalize, encoder/decoder, write out ------
__global__ __launch_bounds__(256) void k4_final(
    const float* __restrict__ x,
    const float* __restrict__ W1, const float* __restrict__ b1,
    const float* __restrict__ W2, const float* __restrict__ b2,
    const float* __restrict__ W3, const float* __restrict__ b3,
    const float* __restrict__ We, const float* __restrict__ be,
    const float* __restrict__ Wd, const float* __restrict__ bd,
    const float* __restrict__ accum, float* __restrict__ out)
{
    int n = blockIdx.x * 256 + threadIdx.x;

    float cn[3], E, ev[7];
    node_feats(x, W1, b1, W2, b2, W3, b3, n, cn, E, ev);

    // accum cols: q=0..6 -> sum w*ev[q]; q=7 -> sum w*E (denominator incl. diagonal)
    float denom = accum[7 * NN + n] - E;
    denom = fmaxf(denom, 1e-30f);
    float inv = 1.0f / denom;

    float inp[14];
#pragma unroll
    for (int d = 0; d < DIN; ++d) inp[d] = x[n * DIN + d];
#pragma unroll
    for (int q = 0; q < 7; ++q) inp[7 + q] = (accum[q * NN + n] - ev[q]) * inv;

    float codes[DH];
#pragma unroll
    for (int k = 0; k < DH; ++k) {
        float t = be[k];
#pragma unroll
        for (int d = 0; d < 14; ++d) t = fmaf(We[k * 14 + d], inp[d], t);
        codes[k] = leaky(t);
    }
#pragma unroll
    for (int cc = 0; cc < DIN; ++cc) {
        float t = bd[cc];
#pragma unroll
        for (int k = 0; k < DH; ++k) t = fmaf(Wd[cc * DH + k], codes[k], t);
        out[(size_t)n * DIN + cc] = t;
    }
}

extern "C" void kernel_launch(void* const* d_in, const int* in_sizes, int n_in,
                              void* d_out, int out_size, void* d_ws, size_t ws_size,
                              hipStream_t stream) {
    const float* x  = (const float*)d_in[0];
    const float* W1 = (const float*)d_in[1];
    const float* b1 = (const float*)d_in[2];
    const float* W2 = (const float*)d_in[3];
    const float* b2 = (const float*)d_in[4];
    const float* W3 = (const float*)d_in[5];
    const float* b3 = (const float*)d_in[6];
    const float* We = (const float*)d_in[7];
    const float* be = (const float*)d_in[8];
    const float* Wd = (const float*)d_in[9];
    const float* bd = (const float*)d_in[10];
    float* out = (float*)d_out;

    float* accum = (float*)d_ws;  // 8 * 8192 * 4 = 262144 B

    hipMemsetAsync(accum, 0, 8 * NN * sizeof(float), stream);
    dim3 g3(NN / ROWS, NN / JC);  // (32, 32) = 1024 blocks
    k3_mfma<<<g3, 256, 0, stream>>>(x, W1, b1, W2, b2, W3, b3, accum);
    k4_final<<<32, 256, 0, stream>>>(x, W1, b1, W2, b2, W3, b3, We, be, Wd, bd, accum, out);
}

// Round 9
// 108.975 us; speedup vs baseline: 1.0642x; 1.0642x over previous
//
#include <hip/hip_runtime.h>

#define NN 8192
#define DIN 7
#define DH 8
#define DOUT 23
#define CUTOFF 3.6f
#define SLOPE 0.01f

#define JC 512               // j-chunk per k3 block
#define ROWS 256             // rows per k3 block (4 waves x 4 tiles x 16)
#define PPITCH 520           // padded row pitch (shorts) for P hi/lo in LDS
#define NJS (JC / 32)        // 16 K-steps of 32

typedef float  v4f __attribute__((ext_vector_type(4)));
typedef short  v8s __attribute__((ext_vector_type(8)));
typedef unsigned int v4u __attribute__((ext_vector_type(4)));

__device__ __forceinline__ float leaky(float v) { return v >= 0.0f ? v : SLOPE * v; }

// Per-node feature pipeline — now computed ONCE per node in k_stage.
__device__ __forceinline__ void node_feats(
    const float* __restrict__ x,
    const float* __restrict__ W1, const float* __restrict__ b1,
    const float* __restrict__ W2, const float* __restrict__ b2,
    const float* __restrict__ W3, const float* __restrict__ b3,
    int n, float coord[3], float& E, float ev[7])
{
    float xi[DIN];
#pragma unroll
    for (int d = 0; d < DIN; ++d) xi[d] = x[n * DIN + d];
    coord[0] = xi[0]; coord[1] = xi[1]; coord[2] = xi[2];

    float h1[DH];
#pragma unroll
    for (int k = 0; k < DH; ++k) {
        float t = b1[k];
#pragma unroll
        for (int d = 0; d < DIN; ++d) t = fmaf(W1[k * DIN + d], xi[d], t);
        h1[k] = leaky(t);
    }
    float h2[DH];
#pragma unroll
    for (int k = 0; k < DH; ++k) {
        float t = b2[k];
#pragma unroll
        for (int d = 0; d < DH; ++d) t = fmaf(W2[k * DH + d], h1[d], t);
        h2[k] = leaky(t);
    }
    float h3[DOUT];
#pragma unroll
    for (int m = 0; m < DOUT; ++m) {
        float t = b3[m];
#pragma unroll
        for (int d = 0; d < DH; ++d) t = fmaf(W3[m * DH + d], h2[d], t);
        h3[m] = t;
    }
    float s = 0.0f;
#pragma unroll
    for (int k = 0; k < 8; ++k) s = fmaf(h3[7 + k], h3[15 + k], s);
    // |s| ~ O(1) -> exp without max-shift safe in fp32; softmax ratio shift-invariant.
    E = expf(s);
#pragma unroll
    for (int q = 0; q < 7; ++q) ev[q] = h3[q] * E;
}

// ---------------- K_stage: once-per-node features -> global; zero accum ------------------
// gPhi/gPlo: bf16 hi/lo of P in [q][j] layout; gEvE[n*8+q]: fp32 (q<7: ev, q=7: E).
__global__ __launch_bounds__(256) void k_stage(
    const float* __restrict__ x,
    const float* __restrict__ W1, const float* __restrict__ b1,
    const float* __restrict__ W2, const float* __restrict__ b2,
    const float* __restrict__ W3, const float* __restrict__ b3,
    float* __restrict__ gCx, float* __restrict__ gCy, float* __restrict__ gCz,
    short* __restrict__ gPhi, short* __restrict__ gPlo,
    float* __restrict__ gEvE, float* __restrict__ accum)
{
    int n = blockIdx.x * 256 + threadIdx.x;
    float c[3], E, ev[7];
    node_feats(x, W1, b1, W2, b2, W3, b3, n, c, E, ev);
    gCx[n] = c[0]; gCy[n] = c[1]; gCz[n] = c[2];
    float pv[8] = {ev[0], ev[1], ev[2], ev[3], ev[4], ev[5], ev[6], E};
#pragma unroll
    for (int q = 0; q < 8; ++q) {
        float v = pv[q];
        unsigned u = __float_as_uint(v);
        float resid = v - __uint_as_float(u & 0xFFFF0000u);   // exact
        gPhi[q * NN + n] = (short)(u >> 16);
        gPlo[q * NN + n] = (short)(__float_as_uint(resid) >> 16);
        gEvE[n * 8 + q] = v;
        accum[q * NN + n] = 0.0f;
    }
}

// ---------------- K3: C(8192x8) = W(0/1 mask) x P via bf16 MFMA, sw-pipelined ------------
// grid (32, 16): blockIdx.x -> 256-row tile, blockIdx.y -> 512-j chunk (R7 config).
// Staging is a pure copy; K-loop register-double-buffers fragments so each lgkmcnt
// wait overlaps the previous step's VALU burst. P rows rotated by 8 shorts/q in LDS
// -> B-frag reads drop from 4-way to free 2-way bank aliasing.
__global__ __launch_bounds__(256, 2) void k3_mfma(
    const float* __restrict__ gCx, const float* __restrict__ gCy,
    const float* __restrict__ gCz,
    const short* __restrict__ gPhi, const short* __restrict__ gPlo,
    float* __restrict__ accum)
{
    __shared__ __attribute__((aligned(16))) float sCx[JC];
    __shared__ __attribute__((aligned(16))) float sCy[JC];
    __shared__ __attribute__((aligned(16))) float sCz[JC];
    __shared__ __attribute__((aligned(16))) short sPhi[8 * PPITCH];
    __shared__ __attribute__((aligned(16))) short sPlo[8 * PPITCH];

    int tid = threadIdx.x;
    int jBase = blockIdx.y * JC;
    int rowBase = blockIdx.x * ROWS;

    // LDS fill: coords straight, P rows rotated by 4 dwords per q (bank swizzle)
    sCx[tid] = gCx[jBase + tid];  sCx[tid + 256] = gCx[jBase + tid + 256];
    sCy[tid] = gCy[jBase + tid];  sCy[tid + 256] = gCy[jBase + tid + 256];
    sCz[tid] = gCz[jBase + tid];  sCz[tid + 256] = gCz[jBase + tid + 256];
#pragma unroll
    for (int q = 0; q < 8; ++q) {
        const unsigned* sh = (const unsigned*)(gPhi + (size_t)q * NN + jBase);
        const unsigned* sl = (const unsigned*)(gPlo + (size_t)q * NN + jBase);
        ((unsigned*)(sPhi + q * PPITCH))[(tid + 4 * q) & 255] = sh[tid];
        ((unsigned*)(sPlo + q * PPITCH))[(tid + 4 * q) & 255] = sl[tid];
    }

    int wave = tid >> 6;
    int lane = tid & 63;
    int lm = lane & 15;      // A-row within tile / C-col (q)
    int q4 = lane >> 4;      // k-slice quad
    int bcol = lm & 7;       // B-row; cols 8-15 mirror 0-7 (never stored)

    // row coords for this lane's 4 tiles
    float rxt[4], ryt[4], rzt[4];
#pragma unroll
    for (int t = 0; t < 4; ++t) {
        int r = rowBase + wave * 64 + t * 16 + lm;
        rxt[t] = gCx[r];
        ryt[t] = gCy[r];
        rzt[t] = gCz[r];
    }

    v4f c0 = {0.f, 0.f, 0.f, 0.f};
    v4f c1 = {0.f, 0.f, 0.f, 0.f};
    v4f c2 = {0.f, 0.f, 0.f, 0.f};
    v4f c3 = {0.f, 0.f, 0.f, 0.f};

    __syncthreads();

#define LOADF(JS, BH, BL, JX, JY, JZ) do {                                   \
        int jb_ = (JS) * 32 + q4 * 8;                                        \
        int jr_ = (jb_ + 8 * bcol) & (JC - 1);                               \
        BH = *(const v8s*)&sPhi[bcol * PPITCH + jr_];                        \
        BL = *(const v8s*)&sPlo[bcol * PPITCH + jr_];                        \
        float4 x0_ = *(const float4*)&sCx[jb_];                              \
        float4 x1_ = *(const float4*)&sCx[jb_ + 4];                          \
        float4 y0_ = *(const float4*)&sCy[jb_];                              \
        float4 y1_ = *(const float4*)&sCy[jb_ + 4];                          \
        float4 z0_ = *(const float4*)&sCz[jb_];                              \
        float4 z1_ = *(const float4*)&sCz[jb_ + 4];                          \
        JX[0]=x0_.x; JX[1]=x0_.y; JX[2]=x0_.z; JX[3]=x0_.w;                  \
        JX[4]=x1_.x; JX[5]=x1_.y; JX[6]=x1_.z; JX[7]=x1_.w;                  \
        JY[0]=y0_.x; JY[1]=y0_.y; JY[2]=y0_.z; JY[3]=y0_.w;                  \
        JY[4]=y1_.x; JY[5]=y1_.y; JY[6]=y1_.z; JY[7]=y1_.w;                  \
        JZ[0]=z0_.x; JZ[1]=z0_.y; JZ[2]=z0_.z; JZ[3]=z0_.w;                  \
        JZ[4]=z1_.x; JZ[5]=z1_.y; JZ[6]=z1_.z; JZ[7]=z1_.w;                  \
    } while (0)

#define COMPUTEF(BH, BL, JX, JY, JZ) do {                                    \
        _Pragma("unroll")                                                    \
        for (int t = 0; t < 4; ++t) {                                        \
            v4u pk;                                                          \
            _Pragma("unroll")                                                \
            for (int i2 = 0; i2 < 4; ++i2) {                                 \
                float ta = fabsf(rxt[t] - JX[2*i2]) + fabsf(ryt[t] - JY[2*i2]) \
                         + fabsf(rzt[t] - JZ[2*i2]);                         \
                float tb = fabsf(rxt[t] - JX[2*i2+1]) + fabsf(ryt[t] - JY[2*i2+1]) \
                         + fabsf(rzt[t] - JZ[2*i2+1]);                       \
                unsigned wa = (ta <= CUTOFF) ? 0x3F80u : 0u;                 \
                unsigned wb = (tb <= CUTOFF) ? 0x3F80u : 0u;                 \
                pk[i2] = wa | (wb << 16);                                    \
            }                                                                \
            v8s a_ = __builtin_bit_cast(v8s, pk);                            \
            v4f* cp = (t == 0) ? &c0 : (t == 1) ? &c1 : (t == 2) ? &c2 : &c3;\
            *cp = __builtin_amdgcn_mfma_f32_16x16x32_bf16(a_, BH, *cp, 0, 0, 0); \
            *cp = __builtin_amdgcn_mfma_f32_16x16x32_bf16(a_, BL, *cp, 0, 0, 0); \
        }                                                                    \
    } while (0)

    v8s bhiA, bloA, bhiB, bloB;
    float jxA[8], jyA[8], jzA[8], jxB[8], jyB[8], jzB[8];

    LOADF(0, bhiA, bloA, jxA, jyA, jzA);
#pragma unroll 1
    for (int js = 0; js < NJS; js += 2) {
        LOADF(js + 1, bhiB, bloB, jxB, jyB, jzB);
        COMPUTEF(bhiA, bloA, jxA, jyA, jzA);
        if (js + 2 < NJS) LOADF(js + 2, bhiA, bloA, jxA, jyA, jzA);
        COMPUTEF(bhiB, bloB, jxB, jyB, jzB);
    }

    // C layout: col=lane&15 (q), row=(lane>>4)*4+reg. Only cols 0..7 are real.
    if (lm < 8) {
        v4f cc[4] = {c0, c1, c2, c3};
#pragma unroll
        for (int t = 0; t < 4; ++t) {
            int rb = rowBase + wave * 64 + t * 16 + q4 * 4;
#pragma unroll
            for (int reg = 0; reg < 4; ++reg)
                atomicAdd(&accum[lm * NN + rb + reg], cc[t][reg]);
        }
    }
#undef LOADF
#undef COMPUTEF
}

// ---------------- K4: finalize from staged E/ev (bit-identical cancel), MLP, store -------
__global__ __launch_bounds__(256) void k4_final(
    const float* __restrict__ x,
    const float* __restrict__ We, const float* __restrict__ be,
    const float* __restrict__ Wd, const float* __restrict__ bd,
    const float* __restrict__ gEvE,
    const float* __restrict__ accum, float* __restrict__ out)
{
    int n = blockIdx.x * 256 + threadIdx.x;

    float4 e0 = *(const float4*)&gEvE[n * 8];
    float4 e1 = *(const float4*)&gEvE[n * 8 + 4];
    float ev[7] = {e0.x, e0.y, e0.z, e0.w, e1.x, e1.y, e1.z};
    float E = e1.w;

    float denom = accum[7 * NN + n] - E;   // remove diagonal (always within cutoff)
    denom = fmaxf(denom, 1e-30f);
    float inv = 1.0f / denom;

    float inp[14];
#pragma unroll
    for (int d = 0; d < DIN; ++d) inp[d] = x[n * DIN + d];
#pragma unroll
    for (int q = 0; q < 7; ++q) inp[7 + q] = (accum[q * NN + n] - ev[q]) * inv;

    float codes[DH];
#pragma unroll
    for (int k = 0; k < DH; ++k) {
        float t = be[k];
#pragma unroll
        for (int d = 0; d < 14; ++d) t = fmaf(We[k * 14 + d], inp[d], t);
        codes[k] = leaky(t);
    }
#pragma unroll
    for (int cc = 0; cc < DIN; ++cc) {
        float t = bd[cc];
#pragma unroll
        for (int k = 0; k < DH; ++k) t = fmaf(Wd[cc * DH + k], codes[k], t);
        out[(size_t)n * DIN + cc] = t;
    }
}

extern "C" void kernel_launch(void* const* d_in, const int* in_sizes, int n_in,
                              void* d_out, int out_size, void* d_ws, size_t ws_size,
                              hipStream_t stream) {
    const float* x  = (const float*)d_in[0];
    const float* W1 = (const float*)d_in[1];
    const float* b1 = (const float*)d_in[2];
    const float* W2 = (const float*)d_in[3];
    const float* b2 = (const float*)d_in[4];
    const float* W3 = (const float*)d_in[5];
    const float* b3 = (const float*)d_in[6];
    const float* We = (const float*)d_in[7];
    const float* be = (const float*)d_in[8];
    const float* Wd = (const float*)d_in[9];
    const float* bd = (const float*)d_in[10];
    float* out = (float*)d_out;

    char* ws = (char*)d_ws;
    float* gCx   = (float*)ws;                     ws += NN * 4;           // 32 KB
    float* gCy   = (float*)ws;                     ws += NN * 4;
    float* gCz   = (float*)ws;                     ws += NN * 4;
    short* gPhi  = (short*)ws;                     ws += 8 * NN * 2;       // 128 KB
    short* gPlo  = (short*)ws;                     ws += 8 * NN * 2;
    float* gEvE  = (float*)ws;                     ws += 8 * NN * 4;       // 256 KB
    float* accum = (float*)ws;                                            // 256 KB

    k_stage<<<32, 256, 0, stream>>>(x, W1, b1, W2, b2, W3, b3,
                                    gCx, gCy, gCz, gPhi, gPlo, gEvE, accum);
    dim3 g3(NN / ROWS, NN / JC);  // (32, 16) = 512 blocks
    k3_mfma<<<g3, 256, 0, stream>>>(gCx, gCy, gCz, gPhi, gPlo, accum);
    k4_final<<<32, 256, 0, stream>>>(x, We, be, Wd, bd, gEvE, accum, out);
}